// Round 1
// baseline (549.143 us; speedup 1.0000x reference)
//
#include <hip/hip_runtime.h>
#include <hip/hip_bf16.h>
#include <stdint.h>

#define N_ROWS 8192   // rows of flat
#define DDIM   1024   // feature dim (GEMM K)
#define KCB    8192   // codebook entries (GEMM N)

typedef __bf16 bf16_t;
typedef __bf16 bf16x4 __attribute__((ext_vector_type(4)));
typedef __bf16 bf16x8 __attribute__((ext_vector_type(8)));
typedef float  f32x4  __attribute__((ext_vector_type(4)));

// ---------------- prep: x fp32 -> bf16 ----------------
__global__ __launch_bounds__(256) void prep_x(const float* __restrict__ x,
                                              bf16_t* __restrict__ xb) {
  int i = blockIdx.x * 256 + threadIdx.x;           // N_ROWS*DDIM/4 elements of float4
  float4 v = ((const float4*)x)[i];
  bf16x4 o = { (bf16_t)v.x, (bf16_t)v.y, (bf16_t)v.z, (bf16_t)v.w };
  *(bf16x4*)(xb + (size_t)i * 4) = o;
}

// ---------------- prep: codebook fp32 -> bf16 + row norms ----------------
__global__ __launch_bounds__(256) void prep_cb(const float* __restrict__ cb,
                                               bf16_t* __restrict__ cbb,
                                               float* __restrict__ norms) {
  int r = blockIdx.x;
  int t = threadIdx.x;
  float4 v = ((const float4*)(cb + (size_t)r * DDIM))[t];
  bf16x4 o = { (bf16_t)v.x, (bf16_t)v.y, (bf16_t)v.z, (bf16_t)v.w };
  *(bf16x4*)(cbb + (size_t)r * DDIM + t * 4) = o;
  float s = v.x*v.x + v.y*v.y + v.z*v.z + v.w*v.w;
  #pragma unroll
  for (int sh = 32; sh > 0; sh >>= 1) s += __shfl_down(s, sh, 64);
  __shared__ float wsum[4];
  int lane = t & 63, w = t >> 6;
  if (lane == 0) wsum[w] = s;
  __syncthreads();
  if (t == 0) norms[r] = wsum[0] + wsum[1] + wsum[2] + wsum[3];
}

// ---------------- fused GEMM (scores = norms - 2*A.B^T) + row argmin ----------------
#define BM 128
#define BN 128
#define BK 32

__global__ __launch_bounds__(256) void gemm_argmin(
    const bf16_t* __restrict__ A,      // [N_ROWS][DDIM]
    const bf16_t* __restrict__ B,      // [KCB][DDIM]  (codebook)
    const float*  __restrict__ norms,  // [KCB]
    unsigned long long* __restrict__ packed)  // [N_ROWS] packed (sortable_val, idx)
{
  __shared__ bf16_t As[BM * BK];
  __shared__ bf16_t Bs[BN * BK];
  const int t    = threadIdx.x;
  const int lane = t & 63;
  const int wid  = t >> 6;
  const int wr   = wid >> 1, wc = wid & 1;   // 2x2 waves, each 64x64
  const int la   = lane & 15, lg = lane >> 4;
  const int brow = blockIdx.x * BM;
  const int bcol = blockIdx.y * BN;

  f32x4 acc[4][4];
  #pragma unroll
  for (int i = 0; i < 4; ++i)
    #pragma unroll
    for (int j = 0; j < 4; ++j) acc[i][j] = (f32x4){0.f, 0.f, 0.f, 0.f};

  for (int kt = 0; kt < DDIM / BK; ++kt) {
    __syncthreads();
    #pragma unroll
    for (int i = 0; i < 2; ++i) {
      int off = i * 256 + t;          // 512 chunks of 8 bf16 (16B)
      int row = off >> 2;             // 4 chunks per 32-wide row
      int c8  = (off & 3) * 8;
      const bf16_t* ga = A + (size_t)(brow + row) * DDIM + kt * BK + c8;
      const bf16_t* gb = B + (size_t)(bcol + row) * DDIM + kt * BK + c8;
      __builtin_amdgcn_global_load_lds((__attribute__((address_space(1))) void*)ga,
                                       (__attribute__((address_space(3))) void*)(As + off * 8),
                                       16, 0, 0);
      __builtin_amdgcn_global_load_lds((__attribute__((address_space(1))) void*)gb,
                                       (__attribute__((address_space(3))) void*)(Bs + off * 8),
                                       16, 0, 0);
    }
    __syncthreads();
    bf16x8 af[4], bfr[4];
    #pragma unroll
    for (int mi = 0; mi < 4; ++mi)
      af[mi] = *(const bf16x8*)(As + (wr * 64 + mi * 16 + la) * BK + lg * 8);
    #pragma unroll
    for (int ni = 0; ni < 4; ++ni)
      bfr[ni] = *(const bf16x8*)(Bs + (wc * 64 + ni * 16 + la) * BK + lg * 8);
    #pragma unroll
    for (int mi = 0; mi < 4; ++mi)
      #pragma unroll
      for (int ni = 0; ni < 4; ++ni)
        acc[mi][ni] = __builtin_amdgcn_mfma_f32_16x16x32_bf16(af[mi], bfr[ni], acc[mi][ni], 0, 0, 0);
  }

  // per-row argmin over this block's 128 columns, then global combine via atomicMin
  float nrm[4]; int colg[4];
  #pragma unroll
  for (int ni = 0; ni < 4; ++ni) {
    colg[ni] = bcol + wc * 64 + ni * 16 + la;
    nrm[ni]  = norms[colg[ni]];
  }
  #pragma unroll
  for (int mi = 0; mi < 4; ++mi) {
    #pragma unroll
    for (int j = 0; j < 4; ++j) {
      float best = nrm[0] - 2.0f * acc[mi][0][j];
      int  bidx  = colg[0];
      #pragma unroll
      for (int ni = 1; ni < 4; ++ni) {
        float v = nrm[ni] - 2.0f * acc[mi][ni][j];
        if (v < best || (v == best && colg[ni] < bidx)) { best = v; bidx = colg[ni]; }
      }
      // reduce across the 16 lanes (same lg group) that hold this row
      #pragma unroll
      for (int s = 1; s < 16; s <<= 1) {
        float ov = __shfl_xor(best, s, 64);
        int   oi = __shfl_xor(bidx, s, 64);
        if (ov < best || (ov == best && oi < bidx)) { best = ov; bidx = oi; }
      }
      if (la == 0) {
        int row = brow + wr * 64 + mi * 16 + lg * 4 + j;
        unsigned int ub = __float_as_uint(best);
        ub = (ub & 0x80000000u) ? ~ub : (ub | 0x80000000u);
        unsigned long long pk = ((unsigned long long)ub << 32) | (unsigned int)bidx;
        atomicMin(packed + row, pk);
      }
    }
  }
}

// ---------------- gather recon = in_cb[x_inds] -> bf16 ----------------
__global__ __launch_bounds__(256) void gather_recon(const float* __restrict__ incb,
                                                    const unsigned long long* __restrict__ p1,
                                                    bf16_t* __restrict__ recon) {
  int n  = blockIdx.x;
  int xi = (int)(p1[n] & 0xffffffffull);
  float4 v = ((const float4*)(incb + (size_t)xi * DDIM))[threadIdx.x];
  bf16x4 o = { (bf16_t)v.x, (bf16_t)v.y, (bf16_t)v.z, (bf16_t)v.w };
  *(bf16x4*)(recon + (size_t)n * DDIM + threadIdx.x * 4) = o;
}

// ---------------- out write + loss partial sums ----------------
__global__ __launch_bounds__(256) void finalize_k(const float* __restrict__ x,
                                                  const float* __restrict__ incb,
                                                  const float* __restrict__ outcb,
                                                  const unsigned long long* __restrict__ p1,
                                                  const unsigned long long* __restrict__ p2,
                                                  float* __restrict__ out,
                                                  double* __restrict__ accum) {
  int n  = blockIdx.x;
  int xi = (int)(p1[n] & 0xffffffffull);
  int ri = (int)(p2[n] & 0xffffffffull);
  int t  = threadIdx.x;
  float4 f = ((const float4*)(x     + (size_t)n  * DDIM))[t];
  float4 a = ((const float4*)(incb  + (size_t)xi * DDIM))[t];
  float4 r = ((const float4*)(outcb + (size_t)ri * DDIM))[t];
  ((float4*)(out + (size_t)n * DDIM))[t] = r;
  float s = 0.f;
  { float d1 = f.x - r.x, d2 = f.x - a.x, d3 = a.x - r.x; s += d1*d1 + d2*d2 + d3*d3; }
  { float d1 = f.y - r.y, d2 = f.y - a.y, d3 = a.y - r.y; s += d1*d1 + d2*d2 + d3*d3; }
  { float d1 = f.z - r.z, d2 = f.z - a.z, d3 = a.z - r.z; s += d1*d1 + d2*d2 + d3*d3; }
  { float d1 = f.w - r.w, d2 = f.w - a.w, d3 = a.w - r.w; s += d1*d1 + d2*d2 + d3*d3; }
  #pragma unroll
  for (int sh = 32; sh > 0; sh >>= 1) s += __shfl_down(s, sh, 64);
  __shared__ float wsum[4];
  int lane = t & 63, w = t >> 6;
  if (lane == 0) wsum[w] = s;
  __syncthreads();
  if (t == 0) atomicAdd(accum, (double)(wsum[0] + wsum[1] + wsum[2] + wsum[3]));
}

__global__ void write_loss(const double* __restrict__ accum, float* __restrict__ loss_out) {
  *loss_out = (float)(1.25 * (*accum) / (double)((size_t)N_ROWS * DDIM));
}

// ---------------- launcher ----------------
extern "C" void kernel_launch(void* const* d_in, const int* in_sizes, int n_in,
                              void* d_out, int out_size, void* d_ws, size_t ws_size,
                              hipStream_t stream) {
  const float* x     = (const float*)d_in[0];
  const float* incb  = (const float*)d_in[1];
  const float* outcb = (const float*)d_in[2];
  float* out = (float*)d_out;
  char*  ws  = (char*)d_ws;
  const size_t MB = 1024 * 1024;

  bf16_t* flatb  = (bf16_t*)(ws);             // 16 MB
  bf16_t* incbb  = (bf16_t*)(ws + 16 * MB);   // 16 MB
  bf16_t* outcbb = (bf16_t*)(ws + 32 * MB);   // 16 MB
  bf16_t* reconb = (bf16_t*)(ws + 48 * MB);   // 16 MB
  float*  norms_in  = (float*)(ws + 64 * MB); // 32 KB
  float*  norms_out = norms_in + KCB;         // 32 KB
  unsigned long long* p1 = (unsigned long long*)(ws + 64 * MB + 64 * 1024); // 64 KB
  unsigned long long* p2 = p1 + N_ROWS;                                     // 64 KB
  double* accum = (double*)(p2 + N_ROWS);

  hipMemsetAsync(p1, 0xFF, 2 * N_ROWS * sizeof(unsigned long long), stream);
  hipMemsetAsync(accum, 0, sizeof(double), stream);

  prep_x <<<N_ROWS * DDIM / 1024, 256, 0, stream>>>(x, flatb);
  prep_cb<<<KCB, 256, 0, stream>>>(incb,  incbb,  norms_in);
  prep_cb<<<KCB, 256, 0, stream>>>(outcb, outcbb, norms_out);

  gemm_argmin<<<dim3(N_ROWS / BM, KCB / BN), 256, 0, stream>>>(flatb, incbb, norms_in, p1);
  gather_recon<<<N_ROWS, 256, 0, stream>>>(incb, p1, reconb);
  gemm_argmin<<<dim3(N_ROWS / BM, KCB / BN), 256, 0, stream>>>(reconb, outcbb, norms_out, p2);

  finalize_k<<<N_ROWS, 256, 0, stream>>>(x, incb, outcb, p1, p2, out, accum);
  write_loss<<<1, 1, 0, stream>>>(accum, out + (size_t)N_ROWS * DDIM);
}